// Round 1
// baseline (268.633 us; speedup 1.0000x reference)
//
#include <hip/hip_runtime.h>
#include <hip/hip_bf16.h>

typedef __attribute__((ext_vector_type(4))) float f32x4;
typedef __attribute__((ext_vector_type(8))) short bf16x8;

#define BB 4
#define C 256
#define N 4096
#define EPSI 1e-5f

__device__ __forceinline__ unsigned short f2bf(float f) {
    unsigned int u = __builtin_bit_cast(unsigned int, f);
    u += 0x7fffu + ((u >> 16) & 1u);
    return (unsigned short)(u >> 16);
}

// ---------------- Kernel 1: BN stats -> scale/shift per channel ----------------
__global__ __launch_bounds__(256) void bn_stats_k(
    const float* __restrict__ x, const float* __restrict__ gamma,
    const float* __restrict__ beta, float* __restrict__ scale, float* __restrict__ shift)
{
    int c = blockIdx.x;
    int tid = threadIdx.x;
    float s = 0.f, s2 = 0.f;
    for (int b = 0; b < BB; ++b) {
        const float4* p = (const float4*)(x + ((size_t)b * C + c) * N);
        for (int i = tid; i < N / 4; i += 256) {
            float4 v = p[i];
            s  += v.x + v.y + v.z + v.w;
            s2 += v.x * v.x + v.y * v.y + v.z * v.z + v.w * v.w;
        }
    }
    for (int m = 1; m < 64; m <<= 1) {
        s  += __shfl_xor(s, m);
        s2 += __shfl_xor(s2, m);
    }
    __shared__ float rs[4], rs2[4];
    int w = tid >> 6;
    if ((tid & 63) == 0) { rs[w] = s; rs2[w] = s2; }
    __syncthreads();
    if (tid == 0) {
        float S  = rs[0] + rs[1] + rs[2] + rs[3];
        float S2 = rs2[0] + rs2[1] + rs2[2] + rs2[3];
        const float inv_n = 1.f / (BB * N);
        float mean = S * inv_n;
        float var  = S2 * inv_n - mean * mean;
        float sc = gamma[c] * rsqrtf(var + EPSI);
        scale[c] = sc;
        shift[c] = beta[c] - mean * sc;
    }
}

// ---------------- Kernel 2: fused BN-apply + QKV projection (bf16 MFMA) ----------------
// C[t,o] = sum_c xn[c,t] * W[o,c] + b[o];  q,k stored [b][n][c]; v stored [b][c][n].
// Softmax scale (1/16) folded into q.
__global__ __launch_bounds__(256) void qkv_gemm_k(
    const float* __restrict__ x, const float* __restrict__ Wqkv, const float* __restrict__ bqkv,
    const float* __restrict__ scale, const float* __restrict__ shift,
    unsigned short* __restrict__ q, unsigned short* __restrict__ kt, unsigned short* __restrict__ v)
{
    __shared__ unsigned short Alds[128 * 40];  // [t][c] transposed, padded 32->40
    __shared__ unsigned short Blds[64 * 40];   // [o][c]
    int tid = threadIdx.x;
    int b  = blockIdx.z;
    int T0 = blockIdx.y * 128;
    int O0 = blockIdx.x * 64;
    int lane = tid & 63;
    int w = tid >> 6;
    int wm = w >> 1, wn = w & 1;
    int g = lane >> 4, l15 = lane & 15;

    f32x4 acc[4][2];
    for (int i = 0; i < 4; ++i)
        for (int j = 0; j < 2; ++j) acc[i][j] = f32x4{0.f, 0.f, 0.f, 0.f};

    int a_c = tid >> 3;          // 0..31
    int a_t = (tid & 7) * 16;    // 0..112
    int b_o = tid >> 2;          // 0..63
    int b_c = (tid & 3) * 8;     // 0,8,16,24

    for (int c0 = 0; c0 < C; c0 += 32) {
        {   // stage A: transpose + BN + bf16
            int cg = c0 + a_c;
            const float4* xp = (const float4*)(x + ((size_t)b * C + cg) * N + T0 + a_t);
            float sc = scale[cg], sh = shift[cg];
            for (int j = 0; j < 4; ++j) {
                float4 vv = xp[j];
                int t = a_t + j * 4;
                Alds[(t + 0) * 40 + a_c] = f2bf(vv.x * sc + sh);
                Alds[(t + 1) * 40 + a_c] = f2bf(vv.y * sc + sh);
                Alds[(t + 2) * 40 + a_c] = f2bf(vv.z * sc + sh);
                Alds[(t + 3) * 40 + a_c] = f2bf(vv.w * sc + sh);
            }
        }
        {   // stage B: W rows
            const float4* wp = (const float4*)(Wqkv + (size_t)(O0 + b_o) * C + c0 + b_c);
            float4 v0 = wp[0], v1 = wp[1];
            int base = b_o * 40 + b_c;
            Blds[base + 0] = f2bf(v0.x); Blds[base + 1] = f2bf(v0.y);
            Blds[base + 2] = f2bf(v0.z); Blds[base + 3] = f2bf(v0.w);
            Blds[base + 4] = f2bf(v1.x); Blds[base + 5] = f2bf(v1.y);
            Blds[base + 6] = f2bf(v1.z); Blds[base + 7] = f2bf(v1.w);
        }
        __syncthreads();
        bf16x8 bfr[2];
        for (int nf = 0; nf < 2; ++nf)
            bfr[nf] = *(const bf16x8*)&Blds[(wn * 32 + nf * 16 + l15) * 40 + g * 8];
        for (int mf = 0; mf < 4; ++mf) {
            bf16x8 afr = *(const bf16x8*)&Alds[(wm * 64 + mf * 16 + l15) * 40 + g * 8];
            for (int nf = 0; nf < 2; ++nf)
                acc[mf][nf] = __builtin_amdgcn_mfma_f32_16x16x32_bf16(afr, bfr[nf], acc[mf][nf], 0, 0, 0);
        }
        __syncthreads();
    }
    // epilogue
    for (int mf = 0; mf < 4; ++mf) {
        for (int nf = 0; nf < 2; ++nf) {
            int o = O0 + wn * 32 + nf * 16 + l15;
            float bias = bqkv[o];
            for (int r = 0; r < 4; ++r) {
                int t = T0 + wm * 64 + mf * 16 + g * 4 + r;
                float val = acc[mf][nf][r] + bias;
                if (O0 < 256) {
                    q[((size_t)b * N + t) * C + o] = f2bf(val * 0.0625f);   // fold 1/sqrt(256)
                } else if (O0 < 512) {
                    kt[((size_t)b * N + t) * C + (o - 256)] = f2bf(val);
                } else {
                    v[((size_t)b * C + (o - 512)) * N + t] = f2bf(val);     // transposed store
                }
            }
        }
    }
}

// ---------------- Kernel 3: flash attention ----------------
// Q-tile 64 rows/block (16/wave), KV-tile 64. Q [b][n][c], K [b][n][c], V [b][c][n].
__global__ __launch_bounds__(256) void attn_k(
    const unsigned short* __restrict__ q, const unsigned short* __restrict__ kt,
    const unsigned short* __restrict__ v, unsigned short* __restrict__ ao)
{
    __shared__ unsigned short Klds[64 * 256];     // [tk][c], XOR-swizzled
    __shared__ unsigned short Vlds[256 * 64];     // [c][tk], XOR-swizzled
    __shared__ unsigned short Plds[4][16 * 64];   // per-wave [qr][tk], XOR-swizzled

    int tid = threadIdx.x;
    int b  = blockIdx.y;
    int Q0 = blockIdx.x * 64;
    int lane = tid & 63;
    int w = tid >> 6;
    int g = lane >> 4, l15 = lane & 15;

    // Q fragments hoisted to registers (rows = lane&15 of this wave's 16-row tile)
    bf16x8 qf[8];
    {
        const unsigned short* qp = q + ((size_t)b * N + Q0 + w * 16 + l15) * C + g * 8;
        for (int kc = 0; kc < 8; ++kc)
            qf[kc] = *(const bf16x8*)(qp + kc * 32);
    }

    f32x4 oacc[16];
    for (int i = 0; i < 16; ++i) oacc[i] = f32x4{0.f, 0.f, 0.f, 0.f};
    float mrow[4], lrow[4];
    for (int r = 0; r < 4; ++r) { mrow[r] = -1e30f; lrow[r] = 0.f; }

    for (int n0 = 0; n0 < N; n0 += 64) {
        // stage K tile: 64 rows x 256 cols, fully coalesced, swizzled
        for (int it = 0; it < 8; ++it) {
            int chunk = tid + it * 256;
            int tk = chunk >> 5, j = chunk & 31;
            int idx = tk * 256 + j * 8;
            idx ^= (tk & 7) << 3;
            *(bf16x8*)&Klds[idx] = *(const bf16x8*)(kt + ((size_t)b * N + n0 + tk) * C + j * 8);
        }
        // stage V tile: 256 rows x 64 cols
        for (int it = 0; it < 8; ++it) {
            int chunk = tid + it * 256;
            int c = chunk >> 3, j = chunk & 7;
            int idx = c * 64 + j * 8;
            idx ^= (c & 7) << 3;
            *(bf16x8*)&Vlds[idx] = *(const bf16x8*)(v + ((size_t)b * C + c) * N + n0 + j * 8);
        }
        __syncthreads();

        // S = Q K^T  (4 col-tiles x 8 K-steps)
        f32x4 s[4];
        for (int ct = 0; ct < 4; ++ct) s[ct] = f32x4{0.f, 0.f, 0.f, 0.f};
        for (int kc = 0; kc < 8; ++kc) {
            for (int ct = 0; ct < 4; ++ct) {
                int tk = ct * 16 + l15;
                int idx = tk * 256 + kc * 32 + g * 8;
                idx ^= (tk & 7) << 3;
                bf16x8 kf = *(const bf16x8*)&Klds[idx];
                s[ct] = __builtin_amdgcn_mfma_f32_16x16x32_bf16(qf[kc], kf, s[ct], 0, 0, 0);
            }
        }

        // online softmax (rows spread over 16-lane groups; all 64 lanes active)
        float alpha[4];
        for (int r = 0; r < 4; ++r) {
            float mx = fmaxf(fmaxf(s[0][r], s[1][r]), fmaxf(s[2][r], s[3][r]));
            for (int off = 1; off < 16; off <<= 1) mx = fmaxf(mx, __shfl_xor(mx, off));
            float mn = fmaxf(mrow[r], mx);
            alpha[r] = __expf(mrow[r] - mn);
            mrow[r] = mn;
            float rs = 0.f;
            for (int ct = 0; ct < 4; ++ct) {
                float p = __expf(s[ct][r] - mn);
                s[ct][r] = p;
                rs += p;
            }
            for (int off = 1; off < 16; off <<= 1) rs += __shfl_xor(rs, off);
            lrow[r] = lrow[r] * alpha[r] + rs;
        }
        for (int f = 0; f < 16; ++f)
            for (int r = 0; r < 4; ++r) oacc[f][r] *= alpha[r];

        // P -> per-wave LDS (bf16, swizzled) to re-lay-out into A-fragments
        for (int ct = 0; ct < 4; ++ct) {
            for (int r = 0; r < 4; ++r) {
                int row = g * 4 + r;
                int idx = row * 64 + ct * 16 + l15;
                idx ^= (row & 7) << 3;
                Plds[w][idx] = f2bf(s[ct][r]);
            }
        }

        // O += P V   (16 col-tiles over c, 2 K-steps over tk)
        for (int ks = 0; ks < 2; ++ks) {
            int pidx = l15 * 64 + ks * 32 + g * 8;
            pidx ^= (l15 & 7) << 3;
            bf16x8 pf = *(const bf16x8*)&Plds[w][pidx];
            for (int cf = 0; cf < 16; ++cf) {
                int c = cf * 16 + l15;
                int vidx = c * 64 + ks * 32 + g * 8;
                vidx ^= (c & 7) << 3;
                bf16x8 vf = *(const bf16x8*)&Vlds[vidx];
                oacc[cf] = __builtin_amdgcn_mfma_f32_16x16x32_bf16(pf, vf, oacc[cf], 0, 0, 0);
            }
        }
        __syncthreads();
    }

    // epilogue: O /= l, store bf16 token-major
    float inv[4];
    for (int r = 0; r < 4; ++r) inv[r] = 1.f / lrow[r];
    for (int cf = 0; cf < 16; ++cf) {
        int c = cf * 16 + l15;
        for (int r = 0; r < 4; ++r) {
            int t = Q0 + w * 16 + g * 4 + r;
            ao[((size_t)b * N + t) * C + c] = f2bf(oacc[cf][r] * inv[r]);
        }
    }
}

// ---------------- Kernel 4: out projection + bias + residual ----------------
// out[b,co,t] = sum_c Wout[co,c]*ao[b,t,c] + bout[co] + x[b,co,t]
__global__ __launch_bounds__(256) void out_gemm_k(
    const unsigned short* __restrict__ ao, const float* __restrict__ Wout,
    const float* __restrict__ bout, const float* __restrict__ x, float* __restrict__ out)
{
    __shared__ unsigned short Alds[64 * 72];    // [co][c], padded 64->72
    __shared__ unsigned short Blds[128 * 72];   // [t][c]
    int tid = threadIdx.x;
    int b   = blockIdx.z;
    int CO0 = blockIdx.y * 64;
    int T0  = blockIdx.x * 128;
    int lane = tid & 63;
    int w = tid >> 6;
    int wm = w >> 1, wn = w & 1;
    int g = lane >> 4, l15 = lane & 15;

    f32x4 acc[2][4];
    for (int i = 0; i < 2; ++i)
        for (int j = 0; j < 4; ++j) acc[i][j] = f32x4{0.f, 0.f, 0.f, 0.f};

    int a_r = tid >> 2;           // 0..63
    int a_cb = (tid & 3) * 16;    // 0..48

    for (int c0 = 0; c0 < C; c0 += 64) {
        {   // stage A: Wout fp32->bf16
            const float4* wp = (const float4*)(Wout + (size_t)(CO0 + a_r) * C + c0 + a_cb);
            for (int j = 0; j < 4; ++j) {
                float4 vv = wp[j];
                int base = a_r * 72 + a_cb + j * 4;
                Alds[base + 0] = f2bf(vv.x);
                Alds[base + 1] = f2bf(vv.y);
                Alds[base + 2] = f2bf(vv.z);
                Alds[base + 3] = f2bf(vv.w);
            }
        }
        // stage B: ao rows (already bf16), 16B copies
        for (int it = 0; it < 4; ++it) {
            int chunk = tid + it * 256;
            int tl = chunk >> 3, j = chunk & 7;
            *(bf16x8*)&Blds[tl * 72 + j * 8] =
                *(const bf16x8*)(ao + ((size_t)b * N + T0 + tl) * C + c0 + j * 8);
        }
        __syncthreads();
        for (int kk = 0; kk < 2; ++kk) {
            bf16x8 bfr[4];
            for (int nf = 0; nf < 4; ++nf)
                bfr[nf] = *(const bf16x8*)&Blds[(wn * 64 + nf * 16 + l15) * 72 + kk * 32 + g * 8];
            for (int mf = 0; mf < 2; ++mf) {
                bf16x8 afr = *(const bf16x8*)&Alds[(wm * 32 + mf * 16 + l15) * 72 + kk * 32 + g * 8];
                for (int nf = 0; nf < 4; ++nf)
                    acc[mf][nf] = __builtin_amdgcn_mfma_f32_16x16x32_bf16(afr, bfr[nf], acc[mf][nf], 0, 0, 0);
            }
        }
        __syncthreads();
    }
    for (int mf = 0; mf < 2; ++mf) {
        for (int nf = 0; nf < 4; ++nf) {
            int t = T0 + wn * 64 + nf * 16 + l15;
            for (int r = 0; r < 4; ++r) {
                int co = CO0 + wm * 32 + mf * 16 + g * 4 + r;
                size_t oidx = ((size_t)b * C + co) * N + t;
                out[oidx] = acc[mf][nf][r] + bout[co] + x[oidx];
            }
        }
    }
}

extern "C" void kernel_launch(void* const* d_in, const int* in_sizes, int n_in,
                              void* d_out, int out_size, void* d_ws, size_t ws_size,
                              hipStream_t stream) {
    const float* x     = (const float*)d_in[0];
    const float* Wqkv  = (const float*)d_in[1];
    const float* bqkv  = (const float*)d_in[2];
    const float* Wout  = (const float*)d_in[3];
    const float* bout  = (const float*)d_in[4];
    const float* gamma = (const float*)d_in[5];
    const float* beta  = (const float*)d_in[6];
    float* out = (float*)d_out;

    char* ws = (char*)d_ws;
    float* scale = (float*)ws;
    float* shift = (float*)(ws + 1024);
    unsigned short* q  = (unsigned short*)(ws + 4096);
    unsigned short* kt = q  + (size_t)BB * N * C;
    unsigned short* v  = kt + (size_t)BB * N * C;
    unsigned short* ao = v  + (size_t)BB * N * C;

    bn_stats_k<<<dim3(C), dim3(256), 0, stream>>>(x, gamma, beta, scale, shift);
    qkv_gemm_k<<<dim3(12, 32, BB), dim3(256), 0, stream>>>(x, Wqkv, bqkv, scale, shift, q, kt, v);
    attn_k<<<dim3(64, BB), dim3(256), 0, stream>>>(q, kt, v, ao);
    out_gemm_k<<<dim3(32, 4, BB), dim3(256), 0, stream>>>(ao, Wout, bout, x, out);
}